// Round 7
// baseline (246.958 us; speedup 1.0000x reference)
//
#include <hip/hip_runtime.h>
#include <math.h>

#define BB 32
#define HH 256
#define WW 256
#define HW (HH*WW)
#define TOT (BB*HW)
#define K_BG 0.1f
#define RELAX 5.0f
#define EPS_D 1e-7

typedef unsigned long long u64;
typedef unsigned short u16;

__device__ __forceinline__ float sigf(float x) { return 1.0f / (1.0f + expf(-x)); }

// ---------------- binary 5x5 dilation as bit-ops -> row masks ----------------
// dmask: dilated-nonzero bitmask; nzmask: raw target bitmask. 4 u64 words/row.
// Block 0 also zeroes the completion counters (ws is re-poisoned every call).
__global__ void k_maskdil(const float* __restrict__ tg, u64* __restrict__ dmask,
                          u64* __restrict__ nzmask, int* __restrict__ cnt) {
    __shared__ u64 nz[20][4];
    __shared__ u64 hd[20][4];
    int blk = blockIdx.x;              // 32 images x 16 bands of 16 rows
    int b = blk >> 4, band = blk & 15;
    int r0 = band * 16;
    int t = threadIdx.x, w = t >> 6;
    if (blk == 0 && t < 33) cnt[t] = 0;    // 32 per-image + 1 global
    const float* img = tg + b * HW;
    for (int rr = 0; rr < 20; ++rr) {
        int rg = r0 + rr - 2;
        float v = (rg >= 0 && rg < HH) ? img[rg * WW + t] : 0.0f;
        u64 bal = __ballot(v != 0.0f);
        if ((t & 63) == 0) nz[rr][w] = bal;
    }
    __syncthreads();
    if (t < 80) {                      // 20 rows x 4 words: horizontal +-2 dilate
        int rr = t >> 2, k = t & 3;
        u64 m = nz[rr][k];
        u64 ml = (k > 0) ? nz[rr][k - 1] : 0ULL;
        u64 mr = (k < 3) ? nz[rr][k + 1] : 0ULL;
        hd[rr][k] = m | (m << 1) | (m << 2) | (m >> 1) | (m >> 2)
                  | (ml >> 62) | (ml >> 63) | (mr << 62) | (mr << 63);
    }
    if (t < 64) {                      // store raw masks for the 16 owned rows
        int rr = t >> 2, k = t & 3;
        nzmask[b * 1024 + (r0 + rr) * 4 + k] = nz[rr + 2][k];
    }
    __syncthreads();
    if (t < 64) {                      // 16 rows x 4 words: vertical +-2 dilate
        int rr = t >> 2, k = t & 3;
        u64 o = hd[rr][k] | hd[rr + 1][k] | hd[rr + 2][k] | hd[rr + 3][k] | hd[rr + 4][k];
        dmask[b * 1024 + (r0 + rr) * 4 + k] = o;
    }
}

// ---------------- mega: EDT-in-registers + dice sums + in-kernel tree fold ----
// One block per row. d never hits memory. Last row-block of an image folds the
// image; last image-finisher computes the final scalar (rocPRIM-style pattern).
__global__ __launch_bounds__(256) void k_mega(const float* __restrict__ preds,
                                              const u64* __restrict__ dmask,
                                              const u64* __restrict__ nzmask,
                                              float4* __restrict__ part1,
                                              float4* __restrict__ part2,
                                              float4* __restrict__ imgout,
                                              int* __restrict__ cnt,
                                              float* __restrict__ out) {
    __shared__ u64 mk[1024];           // 8 KB: image's dilated row masks
    __shared__ u16 gS[WW];
    __shared__ float red[8][4];
    __shared__ int lastA;
    int row = blockIdx.x;              // b*256 + i
    int b = row >> 8, i = row & 255;
    int t = threadIdx.x;

    float p = preds[row * WW + t];     // issued early; consumed after the walk

    const uint4* src4 = (const uint4*)(dmask + b * 1024);
    uint4* mk4 = (uint4*)mk;
    mk4[t] = src4[t];
    mk4[t + 256] = src4[t + 256];
    __syncthreads();

    int j = t, w = j >> 6;
    u64 bitm = 1ULL << (j & 63);
    float tv = (float)((nzmask[b * 1024 + i * 4 + w] >> (j & 63)) & 1ULL);
    int fgbit = (mk[i * 4 + w] & bitm) ? 1 : 0;
    int g0 = 0;
    if (fgbit) {
        int up = 10000;
        for (int k = 1; k <= i; ++k)
            if (!(mk[(i - k) * 4 + w] & bitm)) { up = k; break; }
        int dn = 10000;
        for (int k = 1; k < HH - i; ++k)
            if (!(mk[(i + k) * 4 + w] & bitm)) { dn = k; break; }
        g0 = min(up, dn);
    }
    gS[j] = (u16)g0;
    __syncthreads();

    float gv = (float)g0;
    float best = gv * gv;
    for (int r = 1; r < WW; ++r) {
        float rr = (float)(r * r);
        if (rr >= best) break;
        int jl = j - r, jr = j + r;
        if (jl >= 0) { float v = (float)gS[jl]; best = fminf(best, v * v + rr); }
        if (jr < WW) { float v = (float)gS[jr]; best = fminf(best, v * v + rr); }
    }
    float dv = sqrtf(best);

    float sp = sigf(p);
    float sd = sigf(dv / RELAX);
    float vals[8];
    vals[0] = sp * sd * tv;            // A
    vals[1] = sp * tv;                 // B
    vals[2] = sp * sd;                 // A'
    vals[3] = sp;                      // B'
    vals[4] = sp * (1.0f - (float)fgbit);  // C'
    vals[5] = tv;                      // T
    vals[6] = dv;                      // min
    vals[7] = dv;                      // max
    for (int off = 32; off > 0; off >>= 1) {
        #pragma unroll
        for (int q = 0; q < 6; ++q) vals[q] += __shfl_down(vals[q], off, 64);
        vals[6] = fminf(vals[6], __shfl_down(vals[6], off, 64));
        vals[7] = fmaxf(vals[7], __shfl_down(vals[7], off, 64));
    }
    int wid = t >> 6, lane = t & 63;
    if (lane == 0) {
        #pragma unroll
        for (int q = 0; q < 8; ++q) red[q][wid] = vals[q];
    }
    __syncthreads();
    if (t == 0) {
        float s[8];
        #pragma unroll
        for (int q = 0; q < 6; ++q) s[q] = red[q][0] + red[q][1] + red[q][2] + red[q][3];
        s[6] = fminf(fminf(red[6][0], red[6][1]), fminf(red[6][2], red[6][3]));
        s[7] = fmaxf(fmaxf(red[7][0], red[7][1]), fmaxf(red[7][2], red[7][3]));
        part1[row] = make_float4(s[0], s[1], s[2], s[3]);
        part2[row] = make_float4(s[4], s[5], s[6], s[7]);
        __threadfence();
        int old = atomicAdd(&cnt[b], 1);
        lastA = (old == 255);
    }
    __syncthreads();

    if (lastA) {                       // this block is image b's finisher
        float4 p1 = part1[b * HH + t];
        float4 p2 = part2[b * HH + t];
        float v2[8] = {p1.x, p1.y, p1.z, p1.w, p2.x, p2.y, p2.z, p2.w};
        for (int off = 32; off > 0; off >>= 1) {
            #pragma unroll
            for (int q = 0; q < 6; ++q) v2[q] += __shfl_down(v2[q], off, 64);
            v2[6] = fminf(v2[6], __shfl_down(v2[6], off, 64));
            v2[7] = fmaxf(v2[7], __shfl_down(v2[7], off, 64));
        }
        if (lane == 0) {
            #pragma unroll
            for (int q = 0; q < 8; ++q) red[q][wid] = v2[q];
        }
        __syncthreads();
        int lastB = 0;
        if (t == 0) {
            float A  = red[0][0] + red[0][1] + red[0][2] + red[0][3];
            float Bs = red[1][0] + red[1][1] + red[1][2] + red[1][3];
            float Ap = red[2][0] + red[2][1] + red[2][2] + red[2][3];
            float Bp = red[3][0] + red[3][1] + red[3][2] + red[3][3];
            float Cp = red[4][0] + red[4][1] + red[4][2] + red[4][3];
            float T  = red[5][0] + red[5][1] + red[5][2] + red[5][3];
            float dmn = fminf(fminf(red[6][0], red[6][1]), fminf(red[6][2], red[6][3]));
            float dmx = fmaxf(fmaxf(red[7][0], red[7][1]), fmaxf(red[7][2], red[7][3]));
            float inter, card, any;
            if (dmx > 0.0f) {          // image has foreground
                float smin = sigf(dmn / RELAX);
                float smax = sigf(dmx / RELAX);
                float m = smax - smin;
                float denom = (m > 0.0f) ? m : 1.0f;
                inter = (A - smin * Bs) / denom;        // Σ sp·t·(1-fat) == 0 exactly
                card  = (Ap - smin * Bp) / denom + K_BG * Cp + T;
                any = 1.0f;
            } else {                   // dm = 1 - t; t == 0 everywhere
                inter = 0.0f;
                card = Bp - Bs + T;
                any = 0.0f;
            }
            imgout[b] = make_float4(inter, card, any, 0.0f);
            __threadfence();
            int old2 = atomicAdd(&cnt[32], 1);
            lastB = (old2 == BB - 1);
        }
        if (t == 0 && lastB) {         // global finisher: 32 float4 loads
            double I = 0.0, C = 0.0;
            int any = 0;
            for (int bb = 0; bb < BB; ++bb) {
                float4 v = imgout[bb];
                I += (double)v.x; C += (double)v.y;
                any |= (v.z > 0.0f);
            }
            double dice = 2.0 * I / fmax(C, (double)EPS_D);
            out[0] = any ? (float)(1.0 - dice) : 0.0f;
        }
    }
}

extern "C" void kernel_launch(void* const* d_in, const int* in_sizes, int n_in,
                              void* d_out, int out_size, void* d_ws, size_t ws_size,
                              hipStream_t stream) {
    const float* preds = (const float*)d_in[0];
    const float* tg    = (const float*)d_in[1];
    float* out = (float*)d_out;

    u64* dmask    = (u64*)d_ws;                    // 256 KB
    u64* nzmask   = dmask + BB * 1024;             // 256 KB
    float4* part1 = (float4*)(nzmask + BB * 1024); // 128 KB, 16B-aligned
    float4* part2 = part1 + BB * HH;               // 128 KB
    float4* imgout = part2 + BB * HH;              // 512 B
    int* cnt = (int*)(imgout + BB);                // 33 ints

    hipLaunchKernelGGL(k_maskdil, dim3(BB * 16), dim3(WW), 0, stream, tg, dmask, nzmask, cnt);
    hipLaunchKernelGGL(k_mega, dim3(BB * HH), dim3(WW), 0, stream, preds, dmask, nzmask,
                       part1, part2, imgout, cnt, out);
}

// Round 8
// 95.810 us; speedup vs baseline: 2.5776x; 2.5776x over previous
//
#include <hip/hip_runtime.h>
#include <math.h>

#define BB 32
#define HH 256
#define WW 256
#define HW (HH*WW)
#define K_BG 0.1f
#define RELAX 5.0f
#define EPS_D 1e-7

typedef unsigned long long u64;
typedef unsigned short u16;

__device__ __forceinline__ float sigf(float x) { return 1.0f / (1.0f + expf(-x)); }

__device__ __forceinline__ u64 shflx64(u64 x, int s) {
    return (u64)__shfl_xor((unsigned long long)x, s, 64);
}

// ---------------- binary 5x5 dilation as bit-ops -> row masks ----------------
// dmaskT: dilated mask, WORD-MAJOR  [b][word w][row]   (for k_mega's transpose load)
// nzmask: raw target mask, row-major [b][row][word]
__global__ void k_maskdil(const float* __restrict__ tg, u64* __restrict__ dmaskT,
                          u64* __restrict__ nzmask) {
    __shared__ u64 nz[20][4];
    __shared__ u64 hd[20][4];
    int blk = blockIdx.x;              // 32 images x 16 bands of 16 rows
    int b = blk >> 4, band = blk & 15;
    int r0 = band * 16;
    int t = threadIdx.x, w = t >> 6;
    const float* img = tg + b * HW;
    for (int rr = 0; rr < 20; ++rr) {
        int rg = r0 + rr - 2;
        float v = (rg >= 0 && rg < HH) ? img[rg * WW + t] : 0.0f;
        u64 bal = __ballot(v != 0.0f);
        if ((t & 63) == 0) nz[rr][w] = bal;
    }
    __syncthreads();
    if (t < 80) {                      // 20 rows x 4 words: horizontal +-2 dilate
        int rr = t >> 2, k = t & 3;
        u64 m = nz[rr][k];
        u64 ml = (k > 0) ? nz[rr][k - 1] : 0ULL;
        u64 mr = (k < 3) ? nz[rr][k + 1] : 0ULL;
        hd[rr][k] = m | (m << 1) | (m << 2) | (m >> 1) | (m >> 2)
                  | (ml >> 62) | (ml >> 63) | (mr << 62) | (mr << 63);
    }
    if (t < 64) {                      // raw masks for the 16 owned rows
        int rr = t >> 2, k = t & 3;
        nzmask[b * 1024 + (r0 + rr) * 4 + k] = nz[rr + 2][k];
    }
    __syncthreads();
    if (t < 64) {                      // 16 rows x 4 words: vertical +-2 dilate
        int rr = t >> 2, k = t & 3;
        u64 o = hd[rr][k] | hd[rr + 1][k] | hd[rr + 2][k] | hd[rr + 3][k] | hd[rr + 4][k];
        dmaskT[b * 1024 + k * 256 + (r0 + rr)] = o;   // word-major
    }
}

// ---------------- mega: bit-parallel EDT + dice partials, 4 rows per block ----
// Wave g transposes 64x64 bit tiles (register butterfly) -> per-COLUMN 256-bit
// masks in LDS. Vertical distance = clz/ctz over 4 words (branchless, no serial
// LDS chains). Then the exact early-exit min-plus walk (f32 arithmetic identical
// to the reference separable EDT, incl. the 1e4/1e8 sentinel).
__global__ __launch_bounds__(256) void k_mega(const float* __restrict__ preds,
                                              const u64* __restrict__ dmaskT,
                                              const u64* __restrict__ nzmask,
                                              float4* __restrict__ part1,
                                              float4* __restrict__ part2) {
    __shared__ u64 colT[4 * 256];      // [rowgroup g][col c] : bits = rows 64g..64g+63
    __shared__ u16 gS[4][WW];
    __shared__ float red[8][4];
    int blk = blockIdx.x;              // b*64 + q ; rows 4q..4q+3
    int b = blk >> 6, q = blk & 63;
    int i0 = q * 4;
    int tid = threadIdx.x;
    int lane = tid & 63, wv = tid >> 6;
    int j = tid;                       // this thread's column

    float p[4];
    u64 nzw[4];
    #pragma unroll
    for (int rr = 0; rr < 4; ++rr) {
        p[rr] = preds[(b * HH + i0 + rr) * WW + j];
        nzw[rr] = nzmask[b * 1024 + (i0 + rr) * 4 + (j >> 6)];
    }

    // ---- register bit-transpose: wave wv owns row-group g=wv ----
    const u64* base = dmaskT + b * 1024;
    const u64 L32 = 0x00000000FFFFFFFFULL, L16 = 0x0000FFFF0000FFFFULL,
              L8  = 0x00FF00FF00FF00FFULL, L4  = 0x0F0F0F0F0F0F0F0FULL,
              L2  = 0x3333333333333333ULL, L1  = 0x5555555555555555ULL;
    #pragma unroll
    for (int w = 0; w < 4; ++w) {
        u64 x = base[w * 256 + wv * 64 + lane];   // row (64wv+lane), word w
        u64 pp;
        pp = shflx64(x, 32); x = (lane & 32) ? ((x & ~L32) | ((pp & ~L32) >> 32)) : ((x & L32) | ((pp & L32) << 32));
        pp = shflx64(x, 16); x = (lane & 16) ? ((x & ~L16) | ((pp & ~L16) >> 16)) : ((x & L16) | ((pp & L16) << 16));
        pp = shflx64(x,  8); x = (lane &  8) ? ((x & ~L8 ) | ((pp & ~L8 ) >>  8)) : ((x & L8 ) | ((pp & L8 ) <<  8));
        pp = shflx64(x,  4); x = (lane &  4) ? ((x & ~L4 ) | ((pp & ~L4 ) >>  4)) : ((x & L4 ) | ((pp & L4 ) <<  4));
        pp = shflx64(x,  2); x = (lane &  2) ? ((x & ~L2 ) | ((pp & ~L2 ) >>  2)) : ((x & L2 ) | ((pp & L2 ) <<  2));
        pp = shflx64(x,  1); x = (lane &  1) ? ((x & ~L1 ) | ((pp & ~L1 ) >>  1)) : ((x & L1 ) | ((pp & L1 ) <<  1));
        colT[wv * 256 + w * 64 + lane] = x;       // column (64w+lane), row-group wv
    }
    __syncthreads();

    // ---- branchless vertical distance for 4 pixels (same column) ----
    u64 yw[4];
    #pragma unroll
    for (int g = 0; g < 4; ++g) yw[g] = ~colT[g * 256 + j];   // set bit = zero pixel

    int g0v[4], fgv[4];
    #pragma unroll
    for (int rr = 0; rr < 4; ++rr) {
        int i = i0 + rr;
        int iw = i >> 6, ib = i & 63;
        u64 lowm  = (2ULL << ib) - 1ULL;          // bits 0..ib (ib=63 -> ~0)
        u64 highm = ~((1ULL << ib) - 1ULL);       // bits ib..63
        int pu = -1, pd = -1;
        #pragma unroll
        for (int w = 0; w < 4; ++w) {             // ascending: highest nonzero word wins
            u64 m = (w < iw) ? ~0ULL : ((w == iw) ? lowm : 0ULL);
            u64 z = yw[w] & m;
            int cand = (w << 6) + 63 - __clzll(z);
            pu = z ? cand : pu;
        }
        #pragma unroll
        for (int w = 3; w >= 0; --w) {            // descending: lowest nonzero word wins
            u64 m = (w > iw) ? ~0ULL : ((w == iw) ? highm : 0ULL);
            u64 z = yw[w] & m;
            int cand = (w << 6) + (__ffsll((unsigned long long)z) - 1);
            pd = z ? cand : pd;
        }
        int up = (pu >= 0) ? (i - pu) : 10000;
        int dn = (pd >= 0) ? (pd - i) : 10000;
        int g0 = min(min(up, dn), 10000);
        g0v[rr] = g0;
        fgv[rr] = (int)((~yw[iw] >> ib) & 1ULL);  // dilated-mask bit
        gS[rr][j] = (u16)g0;
    }
    __syncthreads();

    // ---- min-plus walk + dice partials for the 4 pixels ----
    float vals[8];
    #pragma unroll
    for (int qq = 0; qq < 6; ++qq) vals[qq] = 0.0f;
    vals[6] = 1e30f; vals[7] = 0.0f;
    #pragma unroll
    for (int rr = 0; rr < 4; ++rr) {
        float gv = (float)g0v[rr];
        float best = gv * gv;
        for (int r = 1; r < WW; ++r) {
            float rf = (float)(r * r);
            if (rf >= best) break;
            int jl = j - r, jr = j + r;
            if (jl >= 0) { float v = (float)gS[rr][jl]; best = fminf(best, v * v + rf); }
            if (jr < WW) { float v = (float)gS[rr][jr]; best = fminf(best, v * v + rf); }
        }
        float dv = sqrtf(best);
        float sp = sigf(p[rr]);
        float sd = sigf(dv / RELAX);
        float tv = (float)((nzw[rr] >> (j & 63)) & 1ULL);
        vals[0] += sp * sd * tv;                  // A
        vals[1] += sp * tv;                       // B
        vals[2] += sp * sd;                       // A'
        vals[3] += sp;                            // B'
        vals[4] += fgv[rr] ? 0.0f : sp;           // C' = sp*(1-fat)
        vals[5] += tv;                            // T
        vals[6] = fminf(vals[6], dv);
        vals[7] = fmaxf(vals[7], dv);
    }
    for (int off = 32; off > 0; off >>= 1) {
        #pragma unroll
        for (int qq = 0; qq < 6; ++qq) vals[qq] += __shfl_down(vals[qq], off, 64);
        vals[6] = fminf(vals[6], __shfl_down(vals[6], off, 64));
        vals[7] = fmaxf(vals[7], __shfl_down(vals[7], off, 64));
    }
    if (lane == 0) {
        #pragma unroll
        for (int qq = 0; qq < 8; ++qq) red[qq][wv] = vals[qq];
    }
    __syncthreads();
    if (tid == 0) {
        float s[8];
        #pragma unroll
        for (int qq = 0; qq < 6; ++qq) s[qq] = red[qq][0] + red[qq][1] + red[qq][2] + red[qq][3];
        s[6] = fminf(fminf(red[6][0], red[6][1]), fminf(red[6][2], red[6][3]));
        s[7] = fmaxf(fmaxf(red[7][0], red[7][1]), fmaxf(red[7][2], red[7][3]));
        part1[blk] = make_float4(s[0], s[1], s[2], s[3]);
        part2[blk] = make_float4(s[4], s[5], s[6], s[7]);
    }
}

// ---------------- per-image: fold 64 group-partials, apply normalization ------
__global__ void k_img(const float4* __restrict__ part1, const float4* __restrict__ part2,
                      float4* __restrict__ imgout) {
    int b = blockIdx.x, t = threadIdx.x;          // 64 threads = 1 wave
    float4 p1 = part1[b * 64 + t];
    float4 p2 = part2[b * 64 + t];
    float vals[8] = {p1.x, p1.y, p1.z, p1.w, p2.x, p2.y, p2.z, p2.w};
    for (int off = 32; off > 0; off >>= 1) {
        #pragma unroll
        for (int qq = 0; qq < 6; ++qq) vals[qq] += __shfl_down(vals[qq], off, 64);
        vals[6] = fminf(vals[6], __shfl_down(vals[6], off, 64));
        vals[7] = fmaxf(vals[7], __shfl_down(vals[7], off, 64));
    }
    if (t == 0) {
        float A = vals[0], Bs = vals[1], Ap = vals[2], Bp = vals[3];
        float Cp = vals[4], T = vals[5], dmn = vals[6], dmx = vals[7];
        float inter, card, any;
        if (dmx > 0.0f) {              // image has foreground
            float smin = sigf(dmn / RELAX);
            float smax = sigf(dmx / RELAX);
            float m = smax - smin;
            float denom = (m > 0.0f) ? m : 1.0f;
            inter = (A - smin * Bs) / denom;       // Σ sp·t·(1-fat) == 0 exactly
            card  = (Ap - smin * Bp) / denom + K_BG * Cp + T;
            any = 1.0f;
        } else {                       // dm = 1 - t ; t == 0 everywhere
            inter = 0.0f;
            card = Bp - Bs + T;
            any = 0.0f;
        }
        imgout[b] = make_float4(inter, card, any, 0.0f);
    }
}

// ---------------- finalize scalar ----------------
__global__ void k_fin(const float4* __restrict__ imgout, float* __restrict__ out) {
    if (threadIdx.x == 0) {
        double I = 0.0, C = 0.0;
        int any = 0;
        for (int b = 0; b < BB; ++b) {
            float4 v = imgout[b];
            I += (double)v.x; C += (double)v.y;
            any |= (v.z > 0.0f);
        }
        double dice = 2.0 * I / fmax(C, (double)EPS_D);
        out[0] = any ? (float)(1.0 - dice) : 0.0f;
    }
}

extern "C" void kernel_launch(void* const* d_in, const int* in_sizes, int n_in,
                              void* d_out, int out_size, void* d_ws, size_t ws_size,
                              hipStream_t stream) {
    const float* preds = (const float*)d_in[0];
    const float* tg    = (const float*)d_in[1];
    float* out = (float*)d_out;

    u64* dmaskT   = (u64*)d_ws;                    // 256 KB
    u64* nzmask   = dmaskT + BB * 1024;            // 256 KB
    float4* part1 = (float4*)(nzmask + BB * 1024); // 32 KB, 16B-aligned
    float4* part2 = part1 + BB * 64;               // 32 KB
    float4* imgout = part2 + BB * 64;              // 512 B

    hipLaunchKernelGGL(k_maskdil, dim3(BB * 16), dim3(WW), 0, stream, tg, dmaskT, nzmask);
    hipLaunchKernelGGL(k_mega, dim3(BB * 64), dim3(WW), 0, stream, preds, dmaskT, nzmask,
                       part1, part2);
    hipLaunchKernelGGL(k_img, dim3(BB), dim3(64), 0, stream, part1, part2, imgout);
    hipLaunchKernelGGL(k_fin, dim3(1), dim3(64), 0, stream, imgout, out);
}